// Round 7
// baseline (24.398 us; speedup 1.0000x reference)
//
#include <hip/hip_runtime.h>
#include <math.h>

typedef float v2f __attribute__((ext_vector_type(2)));

// Problem constants (match reference)
constexpr int B_ = 8;
constexpr int N_ = 128;
constexpr int H_ = 256;
constexpr int W_ = 256;
constexpr int PIX = H_ * W_;                 // 65536 pixels per batch
constexpr int BLOCK = 512;                   // 4 groups x 128 threads
constexpr int GROUPS = 4;                    // N-split: each group does 32 vortices
constexpr int GT = 128;                      // threads per group
constexpr int NPG = N_ / GROUPS;             // 32 vortices per group
constexpr int PPT = 4;                       // pixels per thread
constexpr int PIX_PER_BLOCK = GT * PPT;      // 512
constexpr int BPB = PIX / PIX_PER_BLOCK;     // 128 blocks per batch

// Packed exp2 with scalar boundaries only where packed ops don't exist.
// Input m <= ~0 (m = sq*a + lc). Packed region is PURE add/mul/fma
// (v_pk_add_f32 / v_pk_fma_f32 exist on CDNA); the clamp (no v_pk_max_f32)
// and the integer exponent injection are done as scalar element ops --
// element extract/insert on ext_vector is register aliasing, not shuffles.
__device__ __forceinline__ v2f fast_exp2_pk(v2f m) {
    // scalar clamp: m >= -120 -> n in [-120,0]; p in [0.707,1.414] has biased
    // exp {126,127}, so injected exponent stays normal (>= 6). No wrap, no denorms.
    const float m0 = fmaxf(m.x, -120.0f);
    const float m1 = fmaxf(m.y, -120.0f);
    const v2f mm = {m0, m1};
    const float MAGIC = 12582912.0f;      // 1.5 * 2^23: round-to-int trick
    const v2f t  = mm + MAGIC;            // low mantissa bits of t = round(m)
    const v2f nf = t - MAGIC;             // round(m) as float
    const v2f f  = mm - nf;               // f in [-0.5, 0.5]
    v2f p = f * 0.0096181291f + 0.0555041087f;   // 2^f Taylor, rel err ~4e-5
    p = p * f + 0.2402264791f;
    p = p * f + 0.6931471806f;
    p = p * f + 1.0f;
    // exponent injection: (bits(t) << 23) == round(m) << 23  (0x4B400000<<23 == 0 mod 2^32)
    const unsigned e0 = ((unsigned)__float_as_int(t.x) << 23) + (unsigned)__float_as_int(p.x);
    const unsigned e1 = ((unsigned)__float_as_int(t.y) << 23) + (unsigned)__float_as_int(p.y);
    return (v2f){__int_as_float((int)e0), __int_as_float((int)e1)};
}

__global__ __launch_bounds__(BLOCK, 8) void gaussian_vorticity_kernel(
    const float* __restrict__ vf,   // [B, N, 4] = (y, x, tau, sigma)
    const float* __restrict__ pts,  // [B, H, W, 2]
    float* __restrict__ out)        // [B, H, W, 1]
{
    __shared__ float4 sv[N_];              // (y, x, a=-log2e/sig2, lc=log2(tau/(pi*sig2)))
    __shared__ float4 partials[GROUPS - 1][GT];

    const int b = blockIdx.x / BPB;
    const int blkPix = (blockIdx.x % BPB) * PIX_PER_BLOCK;
    const int t = threadIdx.x;
    const int g = t >> 7;                  // group 0..3 -> vortices [32g, 32g+32)
    const int tl = t & (GT - 1);

    // Stage transformed vortex params into LDS (first 128 threads)
    if (t < N_) {
        const float4 v = reinterpret_cast<const float4*>(vf)[b * N_ + t];
        const float sig2 = fmaxf(v.w * v.w, 1e-35f);     // guard sigma ~ 0
        const float inv_sig2 = 1.0f / sig2;
        const float c = fmaxf(v.z, 1e-35f) * 0.3183098861837907f * inv_sig2;
        sv[t] = make_float4(v.x, v.y,
                            -1.4426950408889634f * inv_sig2,  // a
                            log2f(c));                         // lc
    }
    __syncthreads();

    // 4 pixels per thread; float4 = 2 (y,x) points
    const float4* pbase = reinterpret_cast<const float4*>(
        pts + (size_t)b * PIX * 2) + (blkPix >> 1);
    const float4 p01 = pbase[tl];          // pixels 2tl, 2tl+1
    const float4 p23 = pbase[tl + GT];     // pixels 256+2tl, 256+2tl+1

    // Repack for 2-wide packed fp32
    const v2f py01 = {p01.x, p01.z}, px01 = {p01.y, p01.w};
    const v2f py23 = {p23.x, p23.z}, px23 = {p23.y, p23.w};

    const float4* svg = sv + (g << 5);     // this group's 32 vortices

    v2f acc01 = {0.0f, 0.0f}, acc23 = {0.0f, 0.0f};
#pragma unroll 4
    for (int n = 0; n < NPG; ++n) {
        const float4 v = svg[n];           // broadcast ds_read_b128
        {
            const v2f dy = py01 - v.x;
            const v2f dx = px01 - v.y;
            v2f sq = dy * dy;
            sq = dx * dx + sq;             // pk_fma
            const v2f m = sq * v.z + v.w;  // pk_fma: sq*a + lc
            acc01 += fast_exp2_pk(m);      // pk_add
        }
        {
            const v2f dy = py23 - v.x;
            const v2f dx = px23 - v.y;
            v2f sq = dy * dy;
            sq = dx * dx + sq;
            const v2f m = sq * v.z + v.w;
            acc23 += fast_exp2_pk(m);
        }
    }

    // Combine the 4 vortex-group partials via LDS
    if (g != 0) {
        partials[g - 1][tl] = make_float4(acc01.x, acc01.y, acc23.x, acc23.y);
    }
    __syncthreads();
    if (g == 0) {
#pragma unroll
        for (int k = 0; k < GROUPS - 1; ++k) {
            const float4 pr = partials[k][tl];
            acc01.x += pr.x; acc01.y += pr.y;
            acc23.x += pr.z; acc23.y += pr.w;
        }
        float2* ob = reinterpret_cast<float2*>(out + (size_t)b * PIX + blkPix);
        ob[tl]      = make_float2(acc01.x, acc01.y);
        ob[tl + GT] = make_float2(acc23.x, acc23.y);
    }
}

extern "C" void kernel_launch(void* const* d_in, const int* in_sizes, int n_in,
                              void* d_out, int out_size, void* d_ws, size_t ws_size,
                              hipStream_t stream) {
    const float* vf  = (const float*)d_in[0];   // [B, N, 4]
    const float* pts = (const float*)d_in[1];   // [B, H, W, 2]
    float* out = (float*)d_out;                 // [B, H, W, 1]

    const int grid = B_ * BPB;                  // 1024 blocks
    gaussian_vorticity_kernel<<<grid, BLOCK, 0, stream>>>(vf, pts, out);
}

// Round 8
// 21.764 us; speedup vs baseline: 1.1210x; 1.1210x over previous
//
#include <hip/hip_runtime.h>
#include <math.h>

// Problem constants (match reference)
constexpr int B_ = 8;
constexpr int N_ = 128;
constexpr int H_ = 256;
constexpr int W_ = 256;
constexpr int PIX = H_ * W_;                 // 65536 pixels per batch
constexpr int BLOCK = 512;                   // 4 groups x 128 threads
constexpr int GROUPS = 4;                    // N-split: each group does 32 vortices
constexpr int GT = 128;                      // threads per group
constexpr int NPG = N_ / GROUPS;             // 32 vortices per group
constexpr int PPT = 4;                       // pixels per thread
constexpr int PIX_PER_BLOCK = GT * PPT;      // 512
constexpr int BPB = PIX / PIX_PER_BLOCK;     // 128 blocks per batch

// Scalar software exp2 for m <= 0: round-to-int bit trick + degree-4 poly.
// 10 VALU ops, runs entirely on the vector pipe (no trans unit).
// (bits(t) << 23) == round(m) << 23 exactly since 0x4B400000<<23 wraps to 0.
__device__ __forceinline__ float soft_exp2(float m) {
    m = fmaxf(m, -126.0f);                    // keeps exponent injection in range
    const float MAGIC = 12582912.0f;          // 1.5 * 2^23
    const float t  = m + MAGIC;               // round(m) in low mantissa bits
    const float f  = m - (t - MAGIC);         // f in [-0.5, 0.5]
    float p = fmaf(f, 0.0096181291f, 0.0555041087f);   // 2^f, rel err ~4e-5
    p = fmaf(p, f, 0.2402264791f);
    p = fmaf(p, f, 0.6931471806f);
    p = fmaf(p, f, 1.0f);
    return __int_as_float(__float_as_int(p) + (__float_as_int(t) << 23));
}

__global__ __launch_bounds__(BLOCK, 4) void gaussian_vorticity_kernel(
    const float* __restrict__ vf,   // [B, N, 4] = (y, x, tau, sigma)
    const float* __restrict__ pts,  // [B, H, W, 2]
    float* __restrict__ out)        // [B, H, W, 1]
{
    __shared__ float4 sv[N_];              // (y, x, a=-log2e/sig2, c=tau/(pi*sig2))
    __shared__ float4 partials[GROUPS - 1][GT];

    const int b = blockIdx.x / BPB;
    const int blkPix = (blockIdx.x % BPB) * PIX_PER_BLOCK;
    const int t = threadIdx.x;
    const int g = t >> 7;                  // group 0..3 -> vortices [32g, 32g+32)
    const int tl = t & (GT - 1);

    // Stage transformed vortex params into LDS (first 128 threads)
    if (t < N_) {
        const float4 v = reinterpret_cast<const float4*>(vf)[b * N_ + t];
        const float inv_sig2 = 1.0f / (v.w * v.w);
        sv[t] = make_float4(v.x, v.y,
                            -1.4426950408889634f * inv_sig2,        // a
                            v.z * 0.3183098861837907f * inv_sig2);  // c
    }
    __syncthreads();

    // 4 pixels per thread; float4 = 2 (y,x) points
    const float4* pbase = reinterpret_cast<const float4*>(
        pts + (size_t)b * PIX * 2) + (blkPix >> 1);
    const float4 p01 = pbase[tl];          // pixels 2tl, 2tl+1
    const float4 p23 = pbase[tl + GT];     // pixels 256+2tl, 256+2tl+1

    const float4* svg = sv + (g << 5);     // this group's 32 vortices

    float acc0 = 0.0f, acc1 = 0.0f, acc2 = 0.0f, acc3 = 0.0f;
#pragma unroll 4
    for (int n = 0; n < NPG; ++n) {
        const float4 v = svg[n];           // broadcast ds_read_b128
        // px0 — hardware exp (trans pipe)
        {
            const float dy = p01.x - v.x, dx = p01.y - v.y;
            const float sq = fmaf(dx, dx, dy * dy);
            acc0 = fmaf(__builtin_amdgcn_exp2f(sq * v.z), v.w, acc0);
        }
        // px1 — software exp (vector pipe)
        {
            const float dy = p01.z - v.x, dx = p01.w - v.y;
            const float sq = fmaf(dx, dx, dy * dy);
            acc1 = fmaf(soft_exp2(sq * v.z), v.w, acc1);
        }
        // px2 — hardware exp
        {
            const float dy = p23.x - v.x, dx = p23.y - v.y;
            const float sq = fmaf(dx, dx, dy * dy);
            acc2 = fmaf(__builtin_amdgcn_exp2f(sq * v.z), v.w, acc2);
        }
        // px3 — software exp
        {
            const float dy = p23.z - v.x, dx = p23.w - v.y;
            const float sq = fmaf(dx, dx, dy * dy);
            acc3 = fmaf(soft_exp2(sq * v.z), v.w, acc3);
        }
    }

    // Combine the 4 vortex-group partials via LDS
    if (g != 0) {
        partials[g - 1][tl] = make_float4(acc0, acc1, acc2, acc3);
    }
    __syncthreads();
    if (g == 0) {
#pragma unroll
        for (int k = 0; k < GROUPS - 1; ++k) {
            const float4 pr = partials[k][tl];
            acc0 += pr.x; acc1 += pr.y; acc2 += pr.z; acc3 += pr.w;
        }
        float2* ob = reinterpret_cast<float2*>(out + (size_t)b * PIX + blkPix);
        ob[tl]      = make_float2(acc0, acc1);
        ob[tl + GT] = make_float2(acc2, acc3);
    }
}

extern "C" void kernel_launch(void* const* d_in, const int* in_sizes, int n_in,
                              void* d_out, int out_size, void* d_ws, size_t ws_size,
                              hipStream_t stream) {
    const float* vf  = (const float*)d_in[0];   // [B, N, 4]
    const float* pts = (const float*)d_in[1];   // [B, H, W, 2]
    float* out = (float*)d_out;                 // [B, H, W, 1]

    const int grid = B_ * BPB;                  // 1024 blocks
    gaussian_vorticity_kernel<<<grid, BLOCK, 0, stream>>>(vf, pts, out);
}

// Round 9
// 17.746 us; speedup vs baseline: 1.3749x; 1.2264x over previous
//
#include <hip/hip_runtime.h>
#include <math.h>

// Problem constants (match reference)
constexpr int B_ = 8;
constexpr int N_ = 128;
constexpr int H_ = 256;
constexpr int W_ = 256;
constexpr int PIX = H_ * W_;                 // 65536 pixels per batch
constexpr int BLOCK = 512;                   // 4 groups x 128 threads
constexpr int GROUPS = 4;                    // N-split: each group does 32 vortices
constexpr int GT = 128;                      // threads per group
constexpr int NPG = N_ / GROUPS;             // 32 vortices per group
constexpr int PPT = 8;                       // pixels per thread
constexpr int PIX_PER_BLOCK = GT * PPT;      // 1024
constexpr int BPB = PIX / PIX_PER_BLOCK;     // 64 blocks per batch

__global__ __launch_bounds__(BLOCK, 4) void gaussian_vorticity_kernel(
    const float* __restrict__ vf,   // [B, N, 4] = (y, x, tau, sigma)
    const float* __restrict__ pts,  // [B, H, W, 2]
    float* __restrict__ out)        // [B, H, W, 1]
{
    // sv: (s, ty, tx, c) with s = sqrt(log2 e)/sigma, ty = -s*y, tx = -s*x,
    // c = tau/(pi*sigma^2).  Then exp(-sq/sig2) = exp2(-(uy^2+ux^2)) with
    // uy = fma(s, py, ty), ux = fma(s, px, tx) -- 5 VALU + 1 exp per pixel.
    __shared__ float4 sv[N_];
    __shared__ float4 part[GROUPS - 1][2][GT];

    const int b = blockIdx.x / BPB;
    const int blkPix = (blockIdx.x % BPB) * PIX_PER_BLOCK;
    const int t = threadIdx.x;
    const int g = t >> 7;                  // group 0..3 -> vortices [32g, 32g+32)
    const int tl = t & (GT - 1);

    if (t < N_) {
        const float4 v = reinterpret_cast<const float4*>(vf)[b * N_ + t];
        const float inv_sig = 1.0f / v.w;
        const float s = 1.2011224087864498f * inv_sig;   // sqrt(log2 e)/sigma
        const float c = v.z * 0.3183098861837907f * inv_sig * inv_sig;
        sv[t] = make_float4(s, -s * v.x, -s * v.y, c);
    }
    __syncthreads();

    // 8 pixels per thread; 4 coalesced float4 loads (2 (y,x) points each)
    const float4* pbase = reinterpret_cast<const float4*>(
        pts + (size_t)b * PIX * 2) + (blkPix >> 1);
    float4 P[4];
#pragma unroll
    for (int k = 0; k < 4; ++k) P[k] = pbase[tl + k * GT];

    const float4* svg = sv + (g << 5);     // this group's 32 vortices

    float acc[PPT] = {0, 0, 0, 0, 0, 0, 0, 0};
#pragma unroll 4
    for (int n = 0; n < NPG; ++n) {
        const float4 v = svg[n];           // broadcast ds_read_b128: (s,ty,tx,c)
#pragma unroll
        for (int k = 0; k < 4; ++k) {
            {   // pixel 2k: (y,x) = (P[k].x, P[k].y)
                const float uy = fmaf(v.x, P[k].x, v.y);
                const float ux = fmaf(v.x, P[k].y, v.z);
                const float m = fmaf(ux, ux, uy * uy);
                acc[2 * k] = fmaf(__builtin_amdgcn_exp2f(-m), v.w, acc[2 * k]);
            }
            {   // pixel 2k+1: (y,x) = (P[k].z, P[k].w)
                const float uy = fmaf(v.x, P[k].z, v.y);
                const float ux = fmaf(v.x, P[k].w, v.z);
                const float m = fmaf(ux, ux, uy * uy);
                acc[2 * k + 1] = fmaf(__builtin_amdgcn_exp2f(-m), v.w, acc[2 * k + 1]);
            }
        }
    }

    // Combine the 4 vortex-group partials via LDS
    if (g != 0) {
        part[g - 1][0][tl] = make_float4(acc[0], acc[1], acc[2], acc[3]);
        part[g - 1][1][tl] = make_float4(acc[4], acc[5], acc[6], acc[7]);
    }
    __syncthreads();
    if (g == 0) {
#pragma unroll
        for (int q = 0; q < GROUPS - 1; ++q) {
            const float4 pa = part[q][0][tl];
            const float4 pb = part[q][1][tl];
            acc[0] += pa.x; acc[1] += pa.y; acc[2] += pa.z; acc[3] += pa.w;
            acc[4] += pb.x; acc[5] += pb.y; acc[6] += pb.z; acc[7] += pb.w;
        }
        float2* ob = reinterpret_cast<float2*>(out + (size_t)b * PIX + blkPix);
#pragma unroll
        for (int k = 0; k < 4; ++k)
            ob[tl + k * GT] = make_float2(acc[2 * k], acc[2 * k + 1]);
    }
}

extern "C" void kernel_launch(void* const* d_in, const int* in_sizes, int n_in,
                              void* d_out, int out_size, void* d_ws, size_t ws_size,
                              hipStream_t stream) {
    const float* vf  = (const float*)d_in[0];   // [B, N, 4]
    const float* pts = (const float*)d_in[1];   // [B, H, W, 2]
    float* out = (float*)d_out;                 // [B, H, W, 1]

    const int grid = B_ * BPB;                  // 512 blocks, 4 waves/SIMD
    gaussian_vorticity_kernel<<<grid, BLOCK, 0, stream>>>(vf, pts, out);
}

// Round 10
// 17.489 us; speedup vs baseline: 1.3950x; 1.0147x over previous
//
#include <hip/hip_runtime.h>
#include <math.h>

// Problem constants (match reference)
constexpr int B_ = 8;
constexpr int N_ = 128;
constexpr int H_ = 256;
constexpr int W_ = 256;
constexpr int PIX = H_ * W_;                 // 65536 pixels per batch
constexpr int BLOCK = 512;                   // 4 groups x 128 threads
constexpr int GROUPS = 4;                    // N-split: each group does 32 vortices
constexpr int GT = 128;                      // threads per group
constexpr int NPG = N_ / GROUPS;             // 32 vortices per group
constexpr int PPT = 4;                       // pixels per thread
constexpr int PIX_PER_BLOCK = GT * PPT;      // 512
constexpr int BPB = PIX / PIX_PER_BLOCK;     // 128 blocks per batch

__global__ __launch_bounds__(BLOCK, 8) void gaussian_vorticity_kernel(
    const float* __restrict__ vf,   // [B, N, 4] = (y, x, tau, sigma)
    const float* __restrict__ pts,  // [B, H, W, 2]
    float* __restrict__ out)        // [B, H, W, 1]
{
    // sv: (s, ty, tx, c) with s = sqrt(log2 e)/sigma, ty = -s*y, tx = -s*x,
    // c = tau/(pi*sigma^2).  exp(-sq/sig2) = exp2(-(uy^2+ux^2)) with
    // uy = fma(s, py, ty), ux = fma(s, px, tx): 5 VALU + 1 exp per pixel
    // (the negation rides exp2's free VOP3 input modifier).
    __shared__ float4 sv[N_];
    __shared__ float4 partials[GROUPS - 1][GT];

    const int b = blockIdx.x / BPB;
    const int blkPix = (blockIdx.x % BPB) * PIX_PER_BLOCK;
    const int t = threadIdx.x;
    const int g = t >> 7;                  // group 0..3 -> vortices [32g, 32g+32)
    const int tl = t & (GT - 1);

    if (t < N_) {
        const float4 v = reinterpret_cast<const float4*>(vf)[b * N_ + t];
        const float inv_sig = 1.0f / v.w;
        const float s = 1.2011224087864498f * inv_sig;   // sqrt(log2 e)/sigma
        const float c = v.z * 0.3183098861837907f * inv_sig * inv_sig;
        sv[t] = make_float4(s, -s * v.x, -s * v.y, c);
    }
    __syncthreads();

    // 4 pixels per thread; float4 = 2 (y,x) points
    const float4* pbase = reinterpret_cast<const float4*>(
        pts + (size_t)b * PIX * 2) + (blkPix >> 1);
    const float4 p01 = pbase[tl];          // pixels 2tl, 2tl+1
    const float4 p23 = pbase[tl + GT];     // pixels 256+2tl, 256+2tl+1

    const float4* svg = sv + (g << 5);     // this group's 32 vortices

    float acc0 = 0.0f, acc1 = 0.0f, acc2 = 0.0f, acc3 = 0.0f;
#pragma unroll 4
    for (int n = 0; n < NPG; ++n) {
        const float4 v = svg[n];           // broadcast ds_read_b128: (s,ty,tx,c)
        {
            const float uy = fmaf(v.x, p01.x, v.y);
            const float ux = fmaf(v.x, p01.y, v.z);
            const float m = fmaf(ux, ux, uy * uy);
            acc0 = fmaf(__builtin_amdgcn_exp2f(-m), v.w, acc0);
        }
        {
            const float uy = fmaf(v.x, p01.z, v.y);
            const float ux = fmaf(v.x, p01.w, v.z);
            const float m = fmaf(ux, ux, uy * uy);
            acc1 = fmaf(__builtin_amdgcn_exp2f(-m), v.w, acc1);
        }
        {
            const float uy = fmaf(v.x, p23.x, v.y);
            const float ux = fmaf(v.x, p23.y, v.z);
            const float m = fmaf(ux, ux, uy * uy);
            acc2 = fmaf(__builtin_amdgcn_exp2f(-m), v.w, acc2);
        }
        {
            const float uy = fmaf(v.x, p23.z, v.y);
            const float ux = fmaf(v.x, p23.w, v.z);
            const float m = fmaf(ux, ux, uy * uy);
            acc3 = fmaf(__builtin_amdgcn_exp2f(-m), v.w, acc3);
        }
    }

    // Combine the 4 vortex-group partials via LDS
    if (g != 0) {
        partials[g - 1][tl] = make_float4(acc0, acc1, acc2, acc3);
    }
    __syncthreads();
    if (g == 0) {
#pragma unroll
        for (int k = 0; k < GROUPS - 1; ++k) {
            const float4 pr = partials[k][tl];
            acc0 += pr.x; acc1 += pr.y; acc2 += pr.z; acc3 += pr.w;
        }
        float2* ob = reinterpret_cast<float2*>(out + (size_t)b * PIX + blkPix);
        ob[tl]      = make_float2(acc0, acc1);
        ob[tl + GT] = make_float2(acc2, acc3);
    }
}

extern "C" void kernel_launch(void* const* d_in, const int* in_sizes, int n_in,
                              void* d_out, int out_size, void* d_ws, size_t ws_size,
                              hipStream_t stream) {
    const float* vf  = (const float*)d_in[0];   // [B, N, 4]
    const float* pts = (const float*)d_in[1];   // [B, H, W, 2]
    float* out = (float*)d_out;                 // [B, H, W, 1]

    const int grid = B_ * BPB;                  // 1024 blocks, 8 waves/SIMD
    gaussian_vorticity_kernel<<<grid, BLOCK, 0, stream>>>(vf, pts, out);
}